// Round 10
// baseline (165.778 us; speedup 1.0000x reference)
//
#include <hip/hip_runtime.h>
#include <hip/hip_bf16.h>
#include <math.h>

// GCN 2-hop + linear(64->2) + log_softmax, N=100000, E=1600000, D=64.
//
// R9 lesson: each dispatch ran far below device saturation. R10 decouples
// the parallelism axes:
//   - partition: 625 blocks x 512 thr (~20 waves/CU) for full-BW edge
//     streaming; small sector-amplified chunk writes are accepted (volume
//     is only ~6.4MB packed; 4-8x amplification ~= 4-8us).
//   - buckets: PSIZE=128 -> 782 buckets; hop/deg kernels run 782 blocks x
//     256 thr, all co-resident (~12 waves/CU), 1KB LDS, no tail.
//   - deg folds dinv into the feature: v2 = dinv*u (float2) so hop1 gathers
//     8B instead of 16B.
// Math (verified R8/R9): v = d*u; z = d^2*(v_self + sum v_src);
//   logit = d*(z_self + sum z_src) + b; out = log_softmax(logit).

#define NODES 100000
#define EDGES 1600000
#define DIM 64

#define PBITS 7
#define PSIZE 128
#define P_BUCKETS 782  // ceil(100000/128)
#define CAP 3072       // edges per bucket (mean 2046, ~22 sigma headroom)

#define PART_BLOCKS 625
#define PART_PAIRS (EDGES / 2 / PART_BLOCKS)  // 1280 pairs per block

#define PROJ_BLOCKS 782
#define NODES_PER_PROJ 128
#define K1_BLOCKS (PART_BLOCKS + PROJ_BLOCKS)

// ---------------------------------------------------------------------------
// K1: role-split partition (blocks [0,625)) + projection (blocks [625,1407)).
__global__ __launch_bounds__(512) void partproj_kernel(
    const void* __restrict__ ei, int* __restrict__ cursor,
    int* __restrict__ ecbuf, const float* __restrict__ x,
    const float* __restrict__ W, float2* __restrict__ u) {
  const int t = threadIdx.x;
  if (blockIdx.x < PART_BLOCKS) {
    // ---------------- partition role ----------------
    __shared__ int shMode;
    __shared__ int lcnt[P_BUCKETS];
    __shared__ int lbase[P_BUCKETS];
    if (t < 64) {
      const int* p = (const int*)ei;
      unsigned long long ball = __ballot(p[2 * t + 1] == 0);
      if (t == 0) shMode = (ball == ~0ULL) ? 1 : 0;
    }
    for (int i = t; i < P_BUCKETS; i += 512) lcnt[i] = 0;
    __syncthreads();
    const int m = shMode;
    const int pbase = blockIdx.x * PART_PAIRS;

    // pass 1: count targets
    if (m) {
      const longlong2* cp =
          (const longlong2*)((const long long*)ei + EDGES) + pbase;
      for (int i = t; i < PART_PAIRS; i += 512) {
        longlong2 v = cp[i];
        atomicAdd(&lcnt[((int)v.x) >> PBITS], 1);
        atomicAdd(&lcnt[((int)v.y) >> PBITS], 1);
      }
    } else {
      const int2* cp = (const int2*)((const int*)ei + EDGES) + pbase;
      for (int i = t; i < PART_PAIRS; i += 512) {
        int2 v = cp[i];
        atomicAdd(&lcnt[v.x >> PBITS], 1);
        atomicAdd(&lcnt[v.y >> PBITS], 1);
      }
    }
    __syncthreads();
    // reserve per-bucket chunks
    for (int i = t; i < P_BUCKETS; i += 512) {
      int c = lcnt[i];
      lbase[i] = c ? atomicAdd(&cursor[i], c) : 0;
      lcnt[i] = 0;  // reuse as local rank cursor
    }
    __syncthreads();

    // pass 2: write packed edges (src<<7 | local_col) into reserved chunks
    if (m) {
      const longlong2* rp = (const longlong2*)ei + pbase;
      const longlong2* cp =
          (const longlong2*)((const long long*)ei + EDGES) + pbase;
      for (int i = t; i < PART_PAIRS; i += 512) {
        longlong2 rv = rp[i];
        longlong2 cv = cp[i];
        {
          int r = (int)rv.x, c = (int)cv.x, bk = c >> PBITS;
          int rel = lbase[bk] + atomicAdd(&lcnt[bk], 1);
          if (rel < CAP)
            ecbuf[bk * CAP + rel] = (r << PBITS) | (c & (PSIZE - 1));
        }
        {
          int r = (int)rv.y, c = (int)cv.y, bk = c >> PBITS;
          int rel = lbase[bk] + atomicAdd(&lcnt[bk], 1);
          if (rel < CAP)
            ecbuf[bk * CAP + rel] = (r << PBITS) | (c & (PSIZE - 1));
        }
      }
    } else {
      const int2* rp = (const int2*)ei + pbase;
      const int2* cp = (const int2*)((const int*)ei + EDGES) + pbase;
      for (int i = t; i < PART_PAIRS; i += 512) {
        int2 rv = rp[i];
        int2 cv = cp[i];
        {
          int bk = cv.x >> PBITS;
          int rel = lbase[bk] + atomicAdd(&lcnt[bk], 1);
          if (rel < CAP)
            ecbuf[bk * CAP + rel] = (rv.x << PBITS) | (cv.x & (PSIZE - 1));
        }
        {
          int bk = cv.y >> PBITS;
          int rel = lbase[bk] + atomicAdd(&lcnt[bk], 1);
          if (rel < CAP)
            ecbuf[bk * CAP + rel] = (rv.y << PBITS) | (cv.y & (PSIZE - 1));
        }
      }
    }
  } else {
    // ---------------- projection role: u[i] = x[i] @ W^T ----------------
    const int nbase = (blockIdx.x - PART_BLOCKS) * NODES_PER_PROJ;
    const int lane16 = t & 15;  // feature quad within node
    const int sub = t >> 4;     // 32 node-slots per pass
    const float4 w0 = *(const float4*)&W[lane16 * 4];
    const float4 w1 = *(const float4*)&W[DIM + lane16 * 4];
    for (int k = sub; k < NODES_PER_PROJ; k += 32) {
      const int node = nbase + k;
      if (node < NODES) {  // uniform within each 16-lane group
        float4 xv = *(const float4*)&x[(size_t)node * DIM + lane16 * 4];
        float p0 = xv.x * w0.x + xv.y * w0.y + xv.z * w0.z + xv.w * w0.w;
        float p1 = xv.x * w1.x + xv.y * w1.y + xv.z * w1.z + xv.w * w1.w;
#pragma unroll
        for (int off = 8; off >= 1; off >>= 1) {
          p0 += __shfl_xor(p0, off, 16);
          p1 += __shfl_xor(p1, off, 16);
        }
        if (lane16 == 0) u[node] = make_float2(p0, p1);
      }
    }
  }
}

// ---------------------------------------------------------------------------
// K2: per-bucket degree histogram -> dv = rsqrt(deg+1), v2 = dv * u.
__global__ __launch_bounds__(256) void deg_kernel(
    const int* __restrict__ cursor, const int* __restrict__ ecbuf,
    const float2* __restrict__ u, float2* __restrict__ v2,
    float* __restrict__ dv) {
  __shared__ int h[PSIZE];
  const int b = blockIdx.x;
  const int t = threadIdx.x;
  if (t < PSIZE) h[t] = 0;
  __syncthreads();
  const int cnt = min(cursor[b], CAP);
  const int4* ep4 = (const int4*)(ecbuf + b * CAP);
  for (int i = t; 4 * i < cnt; i += 256) {
    int4 v = ep4[i];
    int base = 4 * i;
    if (base + 0 < cnt) atomicAdd(&h[v.x & (PSIZE - 1)], 1);
    if (base + 1 < cnt) atomicAdd(&h[v.y & (PSIZE - 1)], 1);
    if (base + 2 < cnt) atomicAdd(&h[v.z & (PSIZE - 1)], 1);
    if (base + 3 < cnt) atomicAdd(&h[v.w & (PSIZE - 1)], 1);
  }
  __syncthreads();
  if (t < PSIZE) {
    const int node = (b << PBITS) + t;
    if (node < NODES) {
      float d = rsqrtf((float)(h[t] + 1));
      float2 uu = u[node];
      dv[node] = d;
      v2[node] = make_float2(d * uu.x, d * uu.y);
    }
  }
}

// ---------------------------------------------------------------------------
// K3: hop 1. z = d^2 * (v_self + sum v_src). 8B gathers.
__global__ __launch_bounds__(256) void hop1_kernel(
    const int* __restrict__ cursor, const int* __restrict__ ecbuf,
    const float2* __restrict__ v2, const float* __restrict__ dv,
    float2* __restrict__ z) {
  __shared__ float ax[PSIZE];
  __shared__ float ay[PSIZE];
  const int b = blockIdx.x;
  const int t = threadIdx.x;
  if (t < PSIZE) {
    ax[t] = 0.f;
    ay[t] = 0.f;
  }
  __syncthreads();
  const int cnt = min(cursor[b], CAP);
  const int4* ep4 = (const int4*)(ecbuf + b * CAP);
  for (int i = t; 4 * i < cnt; i += 256) {
    int4 v = ep4[i];
    int base = 4 * i;
#pragma unroll
    for (int k = 0; k < 4; k++) {
      int pk = (k == 0) ? v.x : (k == 1) ? v.y : (k == 2) ? v.z : v.w;
      if (base + k < cnt) {
        float2 s = v2[pk >> PBITS];
        int l = pk & (PSIZE - 1);
        atomicAdd(&ax[l], s.x);
        atomicAdd(&ay[l], s.y);
      }
    }
  }
  __syncthreads();
  if (t < PSIZE) {
    const int node = (b << PBITS) + t;
    if (node < NODES) {
      float d = dv[node];
      float sc = d * d;
      float2 vs = v2[node];
      z[node] = make_float2(sc * (ax[t] + vs.x), sc * (ay[t] + vs.y));
    }
  }
}

// ---------------------------------------------------------------------------
// K4: hop 2 + bias + log_softmax.
__global__ __launch_bounds__(256) void hop2_kernel(
    const int* __restrict__ cursor, const int* __restrict__ ecbuf,
    const float2* __restrict__ z, const float* __restrict__ dv,
    const float* __restrict__ bias, float2* __restrict__ out) {
  __shared__ float ax[PSIZE];
  __shared__ float ay[PSIZE];
  const int b = blockIdx.x;
  const int t = threadIdx.x;
  if (t < PSIZE) {
    ax[t] = 0.f;
    ay[t] = 0.f;
  }
  __syncthreads();
  const int cnt = min(cursor[b], CAP);
  const int4* ep4 = (const int4*)(ecbuf + b * CAP);
  for (int i = t; 4 * i < cnt; i += 256) {
    int4 v = ep4[i];
    int base = 4 * i;
#pragma unroll
    for (int k = 0; k < 4; k++) {
      int pk = (k == 0) ? v.x : (k == 1) ? v.y : (k == 2) ? v.z : v.w;
      if (base + k < cnt) {
        float2 zv = z[pk >> PBITS];
        int l = pk & (PSIZE - 1);
        atomicAdd(&ax[l], zv.x);
        atomicAdd(&ay[l], zv.y);
      }
    }
  }
  __syncthreads();
  if (t < PSIZE) {
    const int node = (b << PBITS) + t;
    if (node < NODES) {
      float d = dv[node];
      float2 zi = z[node];
      float l0 = d * (ax[t] + zi.x) + bias[0];
      float l1 = d * (ay[t] + zi.y) + bias[1];
      float m = fmaxf(l0, l1);
      float ls = m + logf(expf(l0 - m) + expf(l1 - m));
      out[node] = make_float2(l0 - ls, l1 - ls);
    }
  }
}

// ---------------------------------------------------------------------------
extern "C" void kernel_launch(void* const* d_in, const int* in_sizes, int n_in,
                              void* d_out, int out_size, void* d_ws,
                              size_t ws_size, hipStream_t stream) {
  const float* x = (const float*)d_in[0];
  const void* ei = d_in[1];
  const float* W = (const float*)d_in[2];
  const float* bias = (const float*)d_in[3];
  float2* out = (float2*)d_out;

  char* w = (char*)d_ws;
  size_t off = 0;
  auto alloc = [&](size_t bytes) -> char* {
    char* p = w + off;
    off += (bytes + 255) & ~(size_t)255;
    return p;
  };
  const int NPAD = P_BUCKETS << PBITS;  // 100096
  int* cursor = (int*)alloc(P_BUCKETS * sizeof(int));
  int* ecbuf = (int*)alloc((size_t)P_BUCKETS * CAP * sizeof(int));  // 9.6 MB
  float2* u = (float2*)alloc((size_t)NPAD * sizeof(float2));
  float2* v2 = (float2*)alloc((size_t)NPAD * sizeof(float2));
  float* dv = (float*)alloc((size_t)NPAD * sizeof(float));
  float2* z = (float2*)alloc((size_t)NPAD * sizeof(float2));
  (void)ws_size;

  hipMemsetAsync(cursor, 0, P_BUCKETS * sizeof(int), stream);
  partproj_kernel<<<K1_BLOCKS, 512, 0, stream>>>(ei, cursor, ecbuf, x, W, u);
  deg_kernel<<<P_BUCKETS, 256, 0, stream>>>(cursor, ecbuf, u, v2, dv);
  hop1_kernel<<<P_BUCKETS, 256, 0, stream>>>(cursor, ecbuf, v2, dv, z);
  hop2_kernel<<<P_BUCKETS, 256, 0, stream>>>(cursor, ecbuf, z, dv, bias, out);
}